// Round 6
// baseline (953.936 us; speedup 1.0000x reference)
//
#include <hip/hip_runtime.h>

// LightGCN: N=U+I nodes, D=64 features, E edges (symmetrized to 2E directed).
// CSR built per call via bucket sort (256-row buckets). Row degrees come from
// global atomics in bucket_count; csr_build only scans+scatters. Rows PADDED
// to multiples of 8 with sentinel zero-row N -> branch-free SpMM inner loop.
// x stored pre-scaled: xs[c] = dis[c]*x[c] (bf16x2 packed, row = 128B):
// S = sum xs[c]; x_new = dr*S; xs_next = dr^2*S.
// SpMM: one wave per row; lane=(n8,dp): 8 neighbors per uint4 (16B) load.

static constexpr int D = 64;
#define BSHIFT 8
#define BROWS 256               // rows per bucket
#define KP 1024                 // padded bucket count for scans (>= KB=586)
#define TILE 2048               // entries per bucket_scatter block (256 thr x 8)
#define PADSLACK (7 * BROWS)    // max pad growth per bucket (rows pad to x8)

__device__ __forceinline__ float bflo(unsigned v) {
    unsigned u = v << 16;
    return __builtin_bit_cast(float, u);
}
__device__ __forceinline__ float bfhi(unsigned v) {
    unsigned u = v & 0xFFFF0000u;
    return __builtin_bit_cast(float, u);
}
__device__ __forceinline__ unsigned pack_bf16x2(float a, float b) {
    unsigned ua = __builtin_bit_cast(unsigned, a);
    unsigned ub = __builtin_bit_cast(unsigned, b);
    ua += 0x7FFFu + ((ua >> 16) & 1u);   // RNE
    ub += 0x7FFFu + ((ub >> 16) & 1u);
    return (ua >> 16) | (ub & 0xFFFF0000u);
}

// ---- Pass 0: per-bucket histogram (LDS) + per-row degrees (global atomics) ----
__global__ __launch_bounds__(256) void bucket_count(
        const int* __restrict__ eu, const int* __restrict__ ei,
        int* __restrict__ bcnt, int* __restrict__ deg, int E, int U) {
    __shared__ int h[KP];
    int tid = threadIdx.x;
#pragma unroll
    for (int k = 0; k < 4; ++k) h[tid + k * 256] = 0;
    __syncthreads();
    for (int e = blockIdx.x * blockDim.x + tid; e < E; e += gridDim.x * blockDim.x) {
        int u = eu[e];
        int it = U + ei[e];
        atomicAdd(&h[u >> BSHIFT], 1);
        atomicAdd(&h[it >> BSHIFT], 1);
        atomicAdd(&deg[u], 1);
        atomicAdd(&deg[it], 1);
    }
    __syncthreads();
#pragma unroll
    for (int k = 0; k < 4; ++k) {
        int v = h[tid + k * 256];
        if (v) atomicAdd(&bcnt[tid + k * 256], v);
    }
}

// ---- Pass 1: scan bucket counts -> bucket bases + global cursors ----
__global__ void bscan(const int* __restrict__ bcnt, int* __restrict__ bbase,
                      int* __restrict__ bcursor, int KB, int twoE) {
    __shared__ int s[KP];
    int tid = threadIdx.x; // 1024 threads, 1 block
    int v = (tid < KB) ? bcnt[tid] : 0;
    s[tid] = v;
    __syncthreads();
    for (int off = 1; off < KP; off <<= 1) {
        int a = (tid >= off) ? s[tid - off] : 0;
        __syncthreads();
        s[tid] += a;
        __syncthreads();
    }
    int ex = s[tid] - v; // exclusive
    if (tid < KB) { bbase[tid] = ex; bcursor[tid] = ex; }
    if (tid == KB) bbase[tid] = twoE;
    if (tid > KB) bcursor[tid] = 0;
}

// ---- Pass 2: scatter entries into bucket-grouped pairs buffer ----
// packed entry: (row & 255) << 18 | col   (col < 2^18)
__global__ __launch_bounds__(256) void bucket_scatter(
        const int* __restrict__ eu, const int* __restrict__ ei,
        int* __restrict__ bcursor, unsigned* __restrict__ pairs,
        int E, int U, int twoE) {
    __shared__ int hist[KP];           // counts -> local running cursor
    __shared__ int sbase[KP];          // tile-local exclusive base
    __shared__ int gbase[KP];          // reserved global base
    __shared__ unsigned staging[TILE];
    __shared__ unsigned short sb[TILE];
    int tid = threadIdx.x;
#pragma unroll
    for (int k = 0; k < 4; ++k) hist[tid + k * 256] = 0;
    __syncthreads();
    int base_e = blockIdx.x * TILE;
    int bk[8]; unsigned pk[8];
#pragma unroll
    for (int k = 0; k < 8; ++k) {
        int e = base_e + k * 256 + tid;
        bk[k] = -1;
        if (e < twoE) {
            int r, c;
            if (e < E) { r = eu[e]; c = U + ei[e]; }
            else       { c = eu[e - E]; r = U + ei[e - E]; }
            int b = r >> BSHIFT;
            bk[k] = b;
            pk[k] = ((unsigned)(r & (BROWS - 1)) << 18) | (unsigned)c;
            atomicAdd(&hist[b], 1);
        }
    }
    __syncthreads();
    int cc[4];
#pragma unroll
    for (int k = 0; k < 4; ++k) cc[k] = hist[tid + k * 256];
    for (int off = 1; off < KP; off <<= 1) {
        int a[4];
#pragma unroll
        for (int k = 0; k < 4; ++k) {
            int idx = tid + k * 256;
            a[k] = (idx >= off) ? hist[idx - off] : 0;
        }
        __syncthreads();
#pragma unroll
        for (int k = 0; k < 4; ++k) hist[tid + k * 256] += a[k];
        __syncthreads();
    }
#pragma unroll
    for (int k = 0; k < 4; ++k) {
        int idx = tid + k * 256;
        int e0 = hist[idx] - cc[k];
        sbase[idx] = e0;
        if (cc[k] > 0) gbase[idx] = atomicAdd(&bcursor[idx], cc[k]);
        hist[idx] = e0;     // own-slot overwrite, no cross reads
    }
    __syncthreads();
#pragma unroll
    for (int k = 0; k < 8; ++k) {
        if (bk[k] >= 0) {
            int pos = atomicAdd(&hist[bk[k]], 1);
            staging[pos] = pk[k];
            sb[pos] = (unsigned short)bk[k];
        }
    }
    __syncthreads();
    int tile_n = min(TILE, twoE - base_e);
#pragma unroll
    for (int k = 0; k < 8; ++k) {
        int j = k * 256 + tid;
        if (j < tile_n) {
            int b = sb[j];
            pairs[gbase[b] + (j - sbase[b])] = staging[j];
        }
    }
}

// ---- Pass 3 (lite): per-bucket pad-scan + counting scatter -> row_ptr/cols ----
// 256 threads, one thread per row. Padded base = bbase[b] + 1792*b. deg preloaded.
__global__ __launch_bounds__(256) void csr_build(
        const unsigned* __restrict__ pairs, const int* __restrict__ bbase,
        const int* __restrict__ deg, int* __restrict__ row_ptr,
        int* __restrict__ cols, int N) {
    __shared__ int sc[BROWS];
    __shared__ int cur[BROWS];
    __shared__ int fin[BROWS];
    int tid = threadIdx.x;
    int b = blockIdx.x;
    int lo = bbase[b], hi = bbase[b + 1];
    int cbase = lo + PADSLACK * b;
    int r = (b << BSHIFT) + tid;
    int c = (r < N) ? deg[r] : 0;
    int p = (c + 7) & ~7;
    sc[tid] = p;
    __syncthreads();
    for (int off = 1; off < BROWS; off <<= 1) {
        int a = (tid >= off) ? sc[tid - off] : 0;
        __syncthreads();
        sc[tid] += a;
        __syncthreads();
    }
    int e = sc[tid] - p; // exclusive padded offset within bucket
    if (r < N) row_ptr[r] = cbase + e;
    cur[tid] = e;
    fin[tid] = e + p;
    __syncthreads();
    for (int i = lo + tid; i < hi; i += 256) {
        unsigned pe = pairs[i];
        int pos = atomicAdd(&cur[pe >> 18], 1);
        cols[cbase + pos] = (int)(pe & 0x3FFFFu);
    }
    __syncthreads();
    for (int i = cur[tid]; i < fin[tid]; ++i) cols[cbase + i] = N; // sentinel pad
}

// t handles 8 dims (2 float4 reads, 1 uint4 xs write, 2 float4 acc writes).
// Computes dis = rsqrt(deg+1e-7) inline. Sentinel row N zeroed in BOTH buffers.
__global__ __launch_bounds__(256) void init_kernel(
        const float4* __restrict__ ue4, const float4* __restrict__ ie4,
        const int* __restrict__ deg, float* __restrict__ dis,
        uint4* __restrict__ xsA4, uint4* __restrict__ xsB4,
        float4* __restrict__ acc4, int U8, int N8) {
    int t = blockIdx.x * blockDim.x + threadIdx.x;
    if (t >= N8 + 8) return;
    if (t >= N8) {                        // sentinel zero-row N (both buffers)
        uint4 z = {0u, 0u, 0u, 0u};
        xsA4[t] = z;
        xsB4[t] = z;
        return;
    }
    int row = t >> 3;
    float dv = rsqrtf((float)deg[row] + 1e-7f);
    if ((t & 7) == 0) dis[row] = dv;
    const float4* src = (t < U8) ? (ue4 + 2 * t) : (ie4 + 2 * (t - U8));
    float4 a0 = src[0];
    float4 a1 = src[1];
    acc4[2 * t] = a0;
    acc4[2 * t + 1] = a1;
    uint4 w;
    w.x = pack_bf16x2(dv * a0.x, dv * a0.y);
    w.y = pack_bf16x2(dv * a0.z, dv * a0.w);
    w.z = pack_bf16x2(dv * a1.x, dv * a1.y);
    w.w = pack_bf16x2(dv * a1.z, dv * a1.w);
    xsA4[t] = w;
}

// One wave per row. lane = (n8 = lane>>3 neighbor slot, dp = lane&7 uint4 idx).
// One uint4 load covers 8 neighbor rows per instruction; one ds_bpermute per
// octet broadcasts the 8 cols. Rows padded to x8 with sentinel -> no tail code.
__global__ __launch_bounds__(256) void spmm_kernel(
        const int* __restrict__ row_ptr, const int* __restrict__ deg,
        const float* __restrict__ dis, const int* __restrict__ cols,
        const unsigned* __restrict__ xs, unsigned* __restrict__ xs_next,
        float4* __restrict__ acc4, int N, float final_scale) {
    int wid = blockIdx.x * 4 + (threadIdx.x >> 6);
    if (wid >= N) return;
    int lane = threadIdx.x & 63;
    int n8 = lane >> 3;
    int dp = lane & 7;
    int start = row_ptr[wid];
    int cntp = (deg[wid] + 7) & ~7;
    float dr = dis[wid];
    const int* colp = cols + start;
    int vbase = n8 << 2;       // bpermute byte addr component
    int dpo = dp << 2;         // dword offset within row (uint4 = 4 dwords)
    float s0 = 0.f, s1 = 0.f, s2 = 0.f, s3 = 0.f;
    float s4 = 0.f, s5 = 0.f, s6 = 0.f, s7 = 0.f;
    for (int chunk = 0; chunk < cntp; chunk += 64) {
        int cv = colp[chunk + lane];           // over-read OK (slack at end)
        int nq = min(64, cntp - chunk) >> 3;
        for (int q = 0; q < nq; ++q) {
            int co = __builtin_amdgcn_ds_bpermute((q << 5) + vbase, cv);
            const uint4* p = (const uint4*)(xs + (((unsigned)co) << 5) + dpo);
            uint4 v = *p;
            s0 += bflo(v.x); s1 += bfhi(v.x);
            s2 += bflo(v.y); s3 += bfhi(v.y);
            s4 += bflo(v.z); s5 += bfhi(v.z);
            s6 += bflo(v.w); s7 += bfhi(v.w);
        }
    }
#pragma unroll
    for (int m = 8; m < 64; m <<= 1) {
        s0 += __shfl_xor(s0, m); s1 += __shfl_xor(s1, m);
        s2 += __shfl_xor(s2, m); s3 += __shfl_xor(s3, m);
        s4 += __shfl_xor(s4, m); s5 += __shfl_xor(s5, m);
        s6 += __shfl_xor(s6, m); s7 += __shfl_xor(s7, m);
    }
    if (n8 == 0) {
        float x0 = dr * s0, x1 = dr * s1, x2 = dr * s2, x3 = dr * s3;
        float x4 = dr * s4, x5 = dr * s5, x6 = dr * s6, x7 = dr * s7;
        uint4 w;
        w.x = pack_bf16x2(dr * x0, dr * x1);   // xs_next = dr^2 * S
        w.y = pack_bf16x2(dr * x2, dr * x3);
        w.z = pack_bf16x2(dr * x4, dr * x5);
        w.w = pack_bf16x2(dr * x6, dr * x7);
        ((uint4*)xs_next)[(wid << 3) + dp] = w;
        int o = (wid << 4) + (dp << 1);
        float4 a = acc4[o];
        a.x = (a.x + x0) * final_scale;
        a.y = (a.y + x1) * final_scale;
        a.z = (a.z + x2) * final_scale;
        a.w = (a.w + x3) * final_scale;
        acc4[o] = a;
        float4 b2 = acc4[o + 1];
        b2.x = (b2.x + x4) * final_scale;
        b2.y = (b2.y + x5) * final_scale;
        b2.z = (b2.z + x6) * final_scale;
        b2.w = (b2.w + x7) * final_scale;
        acc4[o + 1] = b2;
    }
}

extern "C" void kernel_launch(void* const* d_in, const int* in_sizes, int n_in,
                              void* d_out, int out_size, void* d_ws, size_t ws_size,
                              hipStream_t stream) {
    const float* ue = (const float*)d_in[0];
    const float* ie = (const float*)d_in[1];
    const int* eu = (const int*)d_in[2];
    const int* ei = (const int*)d_in[3];
    const int U = in_sizes[0] / D; // 100001
    const int I = in_sizes[1] / D; // 50001
    const int N = U + I;           // 150002
    const int E = in_sizes[2];     // 4,000,000
    const int twoE = 2 * E;
    const int KB = (N + BROWS - 1) / BROWS; // 586
    float* out = (float*)d_out;

    char* ws = (char*)d_ws;
    auto alloc = [&](size_t bytes) {
        char* p = ws;
        ws += (bytes + 255) & ~(size_t)255;
        return p;
    };
    int* deg = (int*)alloc((size_t)N * 4);           // } contiguous: one memset
    int* bcnt = (int*)alloc(KP * 4);                 // } covers both
    int* row_ptr = (int*)alloc((size_t)N * 4);
    float* dis = (float*)alloc((size_t)N * 4);
    int* bbase = (int*)alloc((KP + 1) * 4);
    int* bcursor = (int*)alloc(KP * 4);
    int* cols = (int*)alloc(((size_t)twoE + (size_t)PADSLACK * (KB + 1) + 256) * 4);
    unsigned* pairs = (unsigned*)alloc((size_t)twoE * 4);
    unsigned* xsA = (unsigned*)alloc(((size_t)N + 1) * 32 * 4); // bf16x2, +sentinel row
    unsigned* xsB = (unsigned*)alloc(((size_t)N + 1) * 32 * 4);

    size_t z0 = (((size_t)N * 4 + 255) & ~(size_t)255) + KP * 4;
    hipMemsetAsync(deg, 0, z0, stream);  // zeroes deg + bcnt in one dispatch
    bucket_count<<<1024, 256, 0, stream>>>(eu, ei, bcnt, deg, E, U);
    bscan<<<1, KP, 0, stream>>>(bcnt, bbase, bcursor, KB, twoE);
    bucket_scatter<<<(twoE + TILE - 1) / TILE, 256, 0, stream>>>(
        eu, ei, bcursor, pairs, E, U, twoE);
    csr_build<<<KB, BROWS, 0, stream>>>(pairs, bbase, deg, row_ptr, cols, N);

    int N8 = N * 8, U8 = U * 8;
    init_kernel<<<(N8 + 8 + 255) / 256, 256, 0, stream>>>(
        (const float4*)ue, (const float4*)ie, deg, dis,
        (uint4*)xsA, (uint4*)xsB, (float4*)out, U8, N8);

    unsigned* x = xsA;
    unsigned* xn = xsB;
    for (int l = 0; l < 3; ++l) {
        float fs = (l == 2) ? 0.25f : 1.0f;
        spmm_kernel<<<(N + 3) / 4, 256, 0, stream>>>(
            row_ptr, deg, dis, cols, x, xn, (float4*)out, N, fs);
        unsigned* tmp = x; x = xn; xn = tmp;
    }
}

// Round 7
// 668.534 us; speedup vs baseline: 1.4269x; 1.4269x over previous
//
#include <hip/hip_runtime.h>

// LightGCN: N=U+I nodes, D=64 features, E edges (symmetrized to 2E directed).
// CSR built per call via bucket sort (256-row buckets). Degrees/dis come from
// the per-bucket LDS counting-sort histogram in csr_build (NO scattered global
// atomics -- R6 showed those cost 323us via 64B-line write amplification).
// Rows PADDED to multiples of 8 with sentinel zero-row N -> branch-free SpMM.
// x stored pre-scaled: xs[c] = dis[c]*x[c] (bf16x2 packed, row = 128B):
// S = sum xs[c]; x_new = dr*S; xs_next = dr^2*S.
// SpMM: one wave per row; lane=(n8,dp): 8 neighbors per uint4 (16B) load.

static constexpr int D = 64;
#define BSHIFT 8
#define BROWS 256               // rows per bucket
#define KP 1024                 // padded bucket count for scans (>= KB=587)
#define TILE 2048               // entries per bucket_scatter block (256 thr x 8)
#define PADSLACK (7 * BROWS)    // max pad growth per bucket (rows pad to x8)

__device__ __forceinline__ float bflo(unsigned v) {
    unsigned u = v << 16;
    return __builtin_bit_cast(float, u);
}
__device__ __forceinline__ float bfhi(unsigned v) {
    unsigned u = v & 0xFFFF0000u;
    return __builtin_bit_cast(float, u);
}
__device__ __forceinline__ unsigned pack_bf16x2(float a, float b) {
    unsigned ua = __builtin_bit_cast(unsigned, a);
    unsigned ub = __builtin_bit_cast(unsigned, b);
    ua += 0x7FFFu + ((ua >> 16) & 1u);   // RNE
    ub += 0x7FFFu + ((ub >> 16) & 1u);
    return (ua >> 16) | (ub & 0xFFFF0000u);
}

// ---- Pass 0: per-bucket histogram (LDS only; int4-vectorized edge reads) ----
__global__ __launch_bounds__(256) void bucket_count(
        const int* __restrict__ eu, const int* __restrict__ ei,
        int* __restrict__ bcnt, int E, int U) {
    __shared__ int h[KP];
    int tid = threadIdx.x;
#pragma unroll
    for (int k = 0; k < 4; ++k) h[tid + k * 256] = 0;
    __syncthreads();
    int E4 = E >> 2;
    int stride = gridDim.x * blockDim.x;
    int g = blockIdx.x * blockDim.x + tid;
    const int4* eu4 = (const int4*)eu;
    const int4* ei4 = (const int4*)ei;
    for (int e = g; e < E4; e += stride) {
        int4 u = eu4[e];
        int4 it = ei4[e];
        atomicAdd(&h[u.x >> BSHIFT], 1);
        atomicAdd(&h[u.y >> BSHIFT], 1);
        atomicAdd(&h[u.z >> BSHIFT], 1);
        atomicAdd(&h[u.w >> BSHIFT], 1);
        atomicAdd(&h[(U + it.x) >> BSHIFT], 1);
        atomicAdd(&h[(U + it.y) >> BSHIFT], 1);
        atomicAdd(&h[(U + it.z) >> BSHIFT], 1);
        atomicAdd(&h[(U + it.w) >> BSHIFT], 1);
    }
    if (blockIdx.x == 0 && tid < (E - (E4 << 2))) {   // tail (<4 edges)
        int e = (E4 << 2) + tid;
        atomicAdd(&h[eu[e] >> BSHIFT], 1);
        atomicAdd(&h[(U + ei[e]) >> BSHIFT], 1);
    }
    __syncthreads();
#pragma unroll
    for (int k = 0; k < 4; ++k) {
        int v = h[tid + k * 256];
        if (v) atomicAdd(&bcnt[tid + k * 256], v);
    }
}

// ---- Pass 1: scan bucket counts -> bucket bases + global cursors ----
__global__ void bscan(const int* __restrict__ bcnt, int* __restrict__ bbase,
                      int* __restrict__ bcursor, int KB, int twoE) {
    __shared__ int s[KP];
    int tid = threadIdx.x; // 1024 threads, 1 block
    int v = (tid < KB) ? bcnt[tid] : 0;
    s[tid] = v;
    __syncthreads();
    for (int off = 1; off < KP; off <<= 1) {
        int a = (tid >= off) ? s[tid - off] : 0;
        __syncthreads();
        s[tid] += a;
        __syncthreads();
    }
    int ex = s[tid] - v; // exclusive
    if (tid < KB) { bbase[tid] = ex; bcursor[tid] = ex; }
    if (tid == KB) bbase[tid] = twoE;
    if (tid > KB) bcursor[tid] = 0;
}

// ---- Pass 2: scatter entries into bucket-grouped pairs buffer ----
// packed entry: (row & 255) << 18 | col   (col < 2^18)
__global__ __launch_bounds__(256) void bucket_scatter(
        const int* __restrict__ eu, const int* __restrict__ ei,
        int* __restrict__ bcursor, unsigned* __restrict__ pairs,
        int E, int U, int twoE) {
    __shared__ int hist[KP];           // counts -> local running cursor
    __shared__ int sbase[KP];          // tile-local exclusive base
    __shared__ int gbase[KP];          // reserved global base
    __shared__ unsigned staging[TILE];
    __shared__ unsigned short sb[TILE];
    int tid = threadIdx.x;
#pragma unroll
    for (int k = 0; k < 4; ++k) hist[tid + k * 256] = 0;
    __syncthreads();
    int base_e = blockIdx.x * TILE;
    int bk[8]; unsigned pk[8];
#pragma unroll
    for (int k = 0; k < 8; ++k) {
        int e = base_e + k * 256 + tid;
        bk[k] = -1;
        if (e < twoE) {
            int r, c;
            if (e < E) { r = eu[e]; c = U + ei[e]; }
            else       { c = eu[e - E]; r = U + ei[e - E]; }
            int b = r >> BSHIFT;
            bk[k] = b;
            pk[k] = ((unsigned)(r & (BROWS - 1)) << 18) | (unsigned)c;
            atomicAdd(&hist[b], 1);
        }
    }
    __syncthreads();
    int cc[4];
#pragma unroll
    for (int k = 0; k < 4; ++k) cc[k] = hist[tid + k * 256];
    for (int off = 1; off < KP; off <<= 1) {
        int a[4];
#pragma unroll
        for (int k = 0; k < 4; ++k) {
            int idx = tid + k * 256;
            a[k] = (idx >= off) ? hist[idx - off] : 0;
        }
        __syncthreads();
#pragma unroll
        for (int k = 0; k < 4; ++k) hist[tid + k * 256] += a[k];
        __syncthreads();
    }
#pragma unroll
    for (int k = 0; k < 4; ++k) {
        int idx = tid + k * 256;
        int e0 = hist[idx] - cc[k];
        sbase[idx] = e0;
        if (cc[k] > 0) gbase[idx] = atomicAdd(&bcursor[idx], cc[k]);
        hist[idx] = e0;     // own-slot overwrite, no cross reads
    }
    __syncthreads();
#pragma unroll
    for (int k = 0; k < 8; ++k) {
        if (bk[k] >= 0) {
            int pos = atomicAdd(&hist[bk[k]], 1);
            staging[pos] = pk[k];
            sb[pos] = (unsigned short)bk[k];
        }
    }
    __syncthreads();
    int tile_n = min(TILE, twoE - base_e);
#pragma unroll
    for (int k = 0; k < 8; ++k) {
        int j = k * 256 + tid;
        if (j < tile_n) {
            int b = sb[j];
            pairs[gbase[b] + (j - sbase[b])] = staging[j];
        }
    }
}

// ---- Pass 3: per-bucket counting sort -> deg/row_ptr/dis/cols ----
// 256 threads, one thread per row. Padded base = bbase[b] + 1792*b.
__global__ __launch_bounds__(256) void csr_build(
        const unsigned* __restrict__ pairs, const int* __restrict__ bbase,
        int* __restrict__ deg, int* __restrict__ row_ptr, float* __restrict__ dis,
        int* __restrict__ cols, int N) {
    __shared__ int cnt[BROWS];
    __shared__ int cur[BROWS];
    __shared__ int fin[BROWS];
    int tid = threadIdx.x;
    int b = blockIdx.x;
    int lo = bbase[b], hi = bbase[b + 1];
    int cbase = lo + PADSLACK * b;
    cnt[tid] = 0;
    __syncthreads();
    for (int i = lo + tid; i < hi; i += 256) atomicAdd(&cnt[pairs[i] >> 18], 1);
    __syncthreads();
    int c = cnt[tid];
    int p = (c + 7) & ~7;
    cnt[tid] = p;
    __syncthreads();
    for (int off = 1; off < BROWS; off <<= 1) {
        int a = (tid >= off) ? cnt[tid - off] : 0;
        __syncthreads();
        cnt[tid] += a;
        __syncthreads();
    }
    int e = cnt[tid] - p; // exclusive padded offset within bucket
    int r = (b << BSHIFT) + tid;
    if (r < N) {
        deg[r] = c;
        row_ptr[r] = cbase + e;
        dis[r] = rsqrtf((float)c + 1e-7f);
    }
    cur[tid] = e;
    fin[tid] = e + p;
    __syncthreads();
    for (int i = lo + tid; i < hi; i += 256) {
        unsigned pe = pairs[i];
        int pos = atomicAdd(&cur[pe >> 18], 1);
        cols[cbase + pos] = (int)(pe & 0x3FFFFu);
    }
    __syncthreads();
    for (int i = cur[tid]; i < fin[tid]; ++i) cols[cbase + i] = N; // sentinel pad
}

// t handles 8 dims (2 float4 reads, 1 uint4 xs write, 2 float4 acc writes).
// Sentinel row N zeroed in BOTH xs buffers.
__global__ __launch_bounds__(256) void init_kernel(
        const float4* __restrict__ ue4, const float4* __restrict__ ie4,
        const float* __restrict__ dis,
        uint4* __restrict__ xsA4, uint4* __restrict__ xsB4,
        float4* __restrict__ acc4, int U8, int N8) {
    int t = blockIdx.x * blockDim.x + threadIdx.x;
    if (t >= N8 + 8) return;
    if (t >= N8) {                        // sentinel zero-row N (both buffers)
        uint4 z = {0u, 0u, 0u, 0u};
        xsA4[t] = z;
        xsB4[t] = z;
        return;
    }
    float dv = dis[t >> 3];
    const float4* src = (t < U8) ? (ue4 + 2 * t) : (ie4 + 2 * (t - U8));
    float4 a0 = src[0];
    float4 a1 = src[1];
    acc4[2 * t] = a0;
    acc4[2 * t + 1] = a1;
    uint4 w;
    w.x = pack_bf16x2(dv * a0.x, dv * a0.y);
    w.y = pack_bf16x2(dv * a0.z, dv * a0.w);
    w.z = pack_bf16x2(dv * a1.x, dv * a1.y);
    w.w = pack_bf16x2(dv * a1.z, dv * a1.w);
    xsA4[t] = w;
}

// One wave per row. lane = (n8 = lane>>3 neighbor slot, dp = lane&7 uint4 idx).
// One uint4 load covers 8 neighbor rows per instruction; one ds_bpermute per
// octet broadcasts the 8 cols. Rows padded to x8 with sentinel -> no tail code.
__global__ __launch_bounds__(256) void spmm_kernel(
        const int* __restrict__ row_ptr, const int* __restrict__ deg,
        const float* __restrict__ dis, const int* __restrict__ cols,
        const unsigned* __restrict__ xs, unsigned* __restrict__ xs_next,
        float4* __restrict__ acc4, int N, float final_scale) {
    int wid = blockIdx.x * 4 + (threadIdx.x >> 6);
    if (wid >= N) return;
    int lane = threadIdx.x & 63;
    int n8 = lane >> 3;
    int dp = lane & 7;
    int start = row_ptr[wid];
    int cntp = (deg[wid] + 7) & ~7;
    float dr = dis[wid];
    const int* colp = cols + start;
    int vbase = n8 << 2;       // bpermute byte addr component
    int dpo = dp << 2;         // dword offset within row (uint4 = 4 dwords)
    float s0 = 0.f, s1 = 0.f, s2 = 0.f, s3 = 0.f;
    float s4 = 0.f, s5 = 0.f, s6 = 0.f, s7 = 0.f;
    for (int chunk = 0; chunk < cntp; chunk += 64) {
        int cv = colp[chunk + lane];           // over-read OK (slack at end)
        int nq = min(64, cntp - chunk) >> 3;
        for (int q = 0; q < nq; ++q) {
            int co = __builtin_amdgcn_ds_bpermute((q << 5) + vbase, cv);
            const uint4* p = (const uint4*)(xs + (((unsigned)co) << 5) + dpo);
            uint4 v = *p;
            s0 += bflo(v.x); s1 += bfhi(v.x);
            s2 += bflo(v.y); s3 += bfhi(v.y);
            s4 += bflo(v.z); s5 += bfhi(v.z);
            s6 += bflo(v.w); s7 += bfhi(v.w);
        }
    }
#pragma unroll
    for (int m = 8; m < 64; m <<= 1) {
        s0 += __shfl_xor(s0, m); s1 += __shfl_xor(s1, m);
        s2 += __shfl_xor(s2, m); s3 += __shfl_xor(s3, m);
        s4 += __shfl_xor(s4, m); s5 += __shfl_xor(s5, m);
        s6 += __shfl_xor(s6, m); s7 += __shfl_xor(s7, m);
    }
    if (n8 == 0) {
        float x0 = dr * s0, x1 = dr * s1, x2 = dr * s2, x3 = dr * s3;
        float x4 = dr * s4, x5 = dr * s5, x6 = dr * s6, x7 = dr * s7;
        uint4 w;
        w.x = pack_bf16x2(dr * x0, dr * x1);   // xs_next = dr^2 * S
        w.y = pack_bf16x2(dr * x2, dr * x3);
        w.z = pack_bf16x2(dr * x4, dr * x5);
        w.w = pack_bf16x2(dr * x6, dr * x7);
        ((uint4*)xs_next)[(wid << 3) + dp] = w;
        int o = (wid << 4) + (dp << 1);
        float4 a = acc4[o];
        a.x = (a.x + x0) * final_scale;
        a.y = (a.y + x1) * final_scale;
        a.z = (a.z + x2) * final_scale;
        a.w = (a.w + x3) * final_scale;
        acc4[o] = a;
        float4 b2 = acc4[o + 1];
        b2.x = (b2.x + x4) * final_scale;
        b2.y = (b2.y + x5) * final_scale;
        b2.z = (b2.z + x6) * final_scale;
        b2.w = (b2.w + x7) * final_scale;
        acc4[o + 1] = b2;
    }
}

extern "C" void kernel_launch(void* const* d_in, const int* in_sizes, int n_in,
                              void* d_out, int out_size, void* d_ws, size_t ws_size,
                              hipStream_t stream) {
    const float* ue = (const float*)d_in[0];
    const float* ie = (const float*)d_in[1];
    const int* eu = (const int*)d_in[2];
    const int* ei = (const int*)d_in[3];
    const int U = in_sizes[0] / D; // 100001
    const int I = in_sizes[1] / D; // 50001
    const int N = U + I;           // 150002
    const int E = in_sizes[2];     // 4,000,000
    const int twoE = 2 * E;
    const int KB = (N + BROWS - 1) / BROWS; // 587
    float* out = (float*)d_out;

    char* ws = (char*)d_ws;
    auto alloc = [&](size_t bytes) {
        char* p = ws;
        ws += (bytes + 255) & ~(size_t)255;
        return p;
    };
    int* deg = (int*)alloc((size_t)N * 4);
    int* row_ptr = (int*)alloc((size_t)N * 4);
    float* dis = (float*)alloc((size_t)N * 4);
    int* bcnt = (int*)alloc(KP * 4);
    int* bbase = (int*)alloc((KP + 1) * 4);
    int* bcursor = (int*)alloc(KP * 4);
    int* cols = (int*)alloc(((size_t)twoE + (size_t)PADSLACK * (KB + 1) + 256) * 4);
    unsigned* pairs = (unsigned*)alloc((size_t)twoE * 4);
    unsigned* xsA = (unsigned*)alloc(((size_t)N + 1) * 32 * 4); // bf16x2, +sentinel row
    unsigned* xsB = (unsigned*)alloc(((size_t)N + 1) * 32 * 4);

    hipMemsetAsync(bcnt, 0, KP * 4, stream);
    bucket_count<<<1024, 256, 0, stream>>>(eu, ei, bcnt, E, U);
    bscan<<<1, KP, 0, stream>>>(bcnt, bbase, bcursor, KB, twoE);
    bucket_scatter<<<(twoE + TILE - 1) / TILE, 256, 0, stream>>>(
        eu, ei, bcursor, pairs, E, U, twoE);
    csr_build<<<KB, BROWS, 0, stream>>>(pairs, bbase, deg, row_ptr, dis, cols, N);

    int N8 = N * 8, U8 = U * 8;
    init_kernel<<<(N8 + 8 + 255) / 256, 256, 0, stream>>>(
        (const float4*)ue, (const float4*)ie, dis,
        (uint4*)xsA, (uint4*)xsB, (float4*)out, U8, N8);

    unsigned* x = xsA;
    unsigned* xn = xsB;
    for (int l = 0; l < 3; ++l) {
        float fs = (l == 2) ? 0.25f : 1.0f;
        spmm_kernel<<<(N + 3) / 4, 256, 0, stream>>>(
            row_ptr, deg, dis, cols, x, xn, (float4*)out, N, fs);
        unsigned* tmp = x; x = xn; xn = tmp;
    }
}